// Round 3
// baseline (646.758 us; speedup 1.0000x reference)
//
#include <hip/hip_runtime.h>

// Problem constants (S=128, B=16, E=1024, N=16, H=64, L=2048, T=2176)
#define S_Q     128
#define B_B     16
#define E_E     1024
#define N_H     16
#define H_D     64
#define L_C     2048
#define T_T     2176
#define BN_H    256      // B*N
#define M_M     2048     // S*B
#define KC_OFF  2097152               // S*B*E
#define VC_OFF  37748736              // KC_OFF + BN*T*H

typedef __attribute__((ext_vector_type(8))) short short8v;   // 8 bf16 (4 VGPRs) MFMA frag
typedef __attribute__((ext_vector_type(4))) short short4v;
typedef __attribute__((ext_vector_type(4))) float floatx4;   // MFMA accumulator

__device__ __forceinline__ short f2bf(float f) {
  union { float f; unsigned u; } x; x.f = f;
  unsigned r = x.u + 0x7fffu + ((x.u >> 16) & 1u);   // RNE truncate to bf16
  return (short)(r >> 16);
}
__device__ __forceinline__ short4v f2bf4(float4 v) {
  short4v r; r.x = f2bf(v.x); r.y = f2bf(v.y); r.z = f2bf(v.z); r.w = f2bf(v.w);
  return r;
}

// ---------------------------------------------------------------------------
// Kernel 1: copy old K/V cache into the new cache outputs (rows 0..L-1).
// Pure streaming, float4-vectorized, grid-stride.
// ---------------------------------------------------------------------------
__global__ __launch_bounds__(256) void copy_caches(const float4* __restrict__ ksrc,
                                                   const float4* __restrict__ vsrc,
                                                   float* __restrict__ out) {
  float4* __restrict__ kdst = (float4*)(out + KC_OFF);
  float4* __restrict__ vdst = (float4*)(out + VC_OFF);
  const int TH4 = T_T * H_D / 4;              // 34816 float4 per (b,n) in dst
  const long total = (long)BN_H * (L_C * H_D / 4);   // 8388608 float4 per cache
  const long stride = (long)gridDim.x * blockDim.x;
#pragma unroll 1
  for (long i = (long)blockIdx.x * blockDim.x + threadIdx.x; i < total; i += stride) {
    long bn  = i >> 15;                        // / (L*H/4 = 32768)
    long rem = i & 32767;
    long d   = bn * TH4 + rem;
    kdst[d] = ksrc[i];
    vdst[d] = vsrc[i];
  }
}

// ---------------------------------------------------------------------------
// Kernel 2/4: bf16 MFMA GEMM, C[m,n] = X[m,:] . W[n,:] + bias[n]
// X f32 [2048][1024] row-major, W f32 [1024][1024] row-major (both K-contig).
// Tile 64x64x64, 4 waves, each wave 32x32 (2x2 frags of 16x16x32 MFMA).
// mode 0: z selects {Wq->qws bf16 (scaled), Wk->kcache tail, Wv->vcache tail}
// mode 1: plain f32 store to obase (output projection)
// ---------------------------------------------------------------------------
__global__ __launch_bounds__(256) void gemm64(
    const float* __restrict__ X,
    const float* __restrict__ W0, const float* __restrict__ Bi0,
    const float* __restrict__ W1, const float* __restrict__ Bi1,
    const float* __restrict__ W2, const float* __restrict__ Bi2,
    short* __restrict__ qws, float* __restrict__ obase, int mode)
{
  __shared__ short lA[64 * 64];
  __shared__ short lB[64 * 64];
  const int z   = blockIdx.z;
  const float* W  = (z == 0) ? W0 : (z == 1) ? W1 : W2;
  const float* Bi = (z == 0) ? Bi0 : (z == 1) ? Bi1 : Bi2;
  const int gr0 = blockIdx.x * 64;
  const int gc0 = blockIdx.y * 64;
  const int tid = threadIdx.x;
  const int lane = tid & 63;
  const int wid  = tid >> 6;
  const int wm = (wid & 1) * 32;
  const int wn = (wid >> 1) * 32;
  const int c = lane & 15;
  const int g = lane >> 4;

  floatx4 zero4 = {0.f, 0.f, 0.f, 0.f};
  floatx4 acc[2][2];
  acc[0][0] = zero4; acc[0][1] = zero4; acc[1][0] = zero4; acc[1][1] = zero4;

  int srow[4], scol[4];
  float4 ra[4], rb[4];
#pragma unroll
  for (int j = 0; j < 4; ++j) { int idx = tid + j * 256; srow[j] = idx >> 4; scol[j] = (idx & 15) * 4; }

  auto stage_load = [&](int kt) {
#pragma unroll
    for (int j = 0; j < 4; ++j) {
      ra[j] = *(const float4*)&X[(long)(gr0 + srow[j]) * 1024 + kt * 64 + scol[j]];
      rb[j] = *(const float4*)&W[(long)(gc0 + srow[j]) * 1024 + kt * 64 + scol[j]];
    }
  };
  stage_load(0);

  for (int kt = 0; kt < 16; ++kt) {
    __syncthreads();                       // LDS free from previous compute
#pragma unroll
    for (int j = 0; j < 4; ++j) {
      int sidx = (srow[j] * 64 + scol[j]) ^ ((srow[j] & 7) << 3);   // XOR swizzle (G4)
      *(short4v*)&lA[sidx] = f2bf4(ra[j]);
      *(short4v*)&lB[sidx] = f2bf4(rb[j]);
    }
    __syncthreads();
    if (kt < 15) stage_load(kt + 1);       // prefetch overlaps MFMA below
#pragma unroll
    for (int ks = 0; ks < 2; ++ks) {
      short8v af[2], bf[2];
#pragma unroll
      for (int mi = 0; mi < 2; ++mi) {
        int row = wm + mi * 16 + c;
        af[mi] = *(const short8v*)&lA[(row * 64 + ks * 32 + g * 8) ^ ((c & 7) << 3)];
      }
#pragma unroll
      for (int ni = 0; ni < 2; ++ni) {
        int row = wn + ni * 16 + c;
        bf[ni] = *(const short8v*)&lB[(row * 64 + ks * 32 + g * 8) ^ ((c & 7) << 3)];
      }
#pragma unroll
      for (int mi = 0; mi < 2; ++mi)
#pragma unroll
        for (int ni = 0; ni < 2; ++ni)
          acc[mi][ni] = __builtin_amdgcn_mfma_f32_16x16x32_bf16(af[mi], bf[ni], acc[mi][ni], 0, 0, 0);
    }
  }

  // Epilogue. C/D layout: col = lane&15, row = (lane>>4)*4 + reg   [m89]
#pragma unroll
  for (int mi = 0; mi < 2; ++mi) {
#pragma unroll
    for (int ni = 0; ni < 2; ++ni) {
#pragma unroll
      for (int r = 0; r < 4; ++r) {
        int m = gr0 + wm + mi * 16 + g * 4 + r;
        int n = gc0 + wn + ni * 16 + c;
        float v = acc[mi][ni][r] + Bi[n];
        if (mode == 1) {
          obase[(long)m * 1024 + n] = v;
        } else {
          int s = m >> 4, b = m & 15, nh = n >> 6, h = n & 63;
          if (z == 0) {
            // q scaled by H^-0.5, bf16, layout [b*N+n][s][h]
            qws[(((long)(b * 16 + nh) * 128 + s) << 6) + h] = f2bf(v * 0.125f);
          } else {
            long off = (z == 1) ? (long)KC_OFF : (long)VC_OFF;
            obase[off + (((long)(b * 16 + nh) * T_T + L_C + s) << 6) + h] = v;
          }
        }
      }
    }
  }
}

// ---------------------------------------------------------------------------
// Kernel 3: flash attention. 1 block per head (256 blocks), 512 threads
// (8 waves x 16 q-rows). KV tiles of 64 rows staged f32->bf16 into LDS
// (K XOR-swizzled; V transposed into [64][72] padded). Online softmax with
// 16-lane shfl_xor reductions; P via per-wave LDS region (wave-private).
// ---------------------------------------------------------------------------
__global__ __launch_bounds__(512) void attn_kernel(const short* __restrict__ qws,
                                                   const float* __restrict__ dout,
                                                   float* __restrict__ ctx)
{
  __shared__ short lK[64 * 64];
  __shared__ short lV[64 * 72];         // V^T [h][kv], rows padded to 72
  __shared__ short lP[8 * 16 * 72];     // per-wave P [16 q][64 keys], padded

  const int bn = blockIdx.x;
  const int tid = threadIdx.x;
  const int lane = tid & 63;
  const int wid  = tid >> 6;
  const int c = lane & 15;
  const int g = lane >> 4;
  const float* kcache = dout + KC_OFF + (long)bn * (T_T * H_D);
  const float* vcache = dout + VC_OFF + (long)bn * (T_T * H_D);

  // Q A-frags, held in registers for the whole loop
  short8v aq[2];
#pragma unroll
  for (int ks = 0; ks < 2; ++ks)
    aq[ks] = *(const short8v*)&qws[(((long)bn * 128 + wid * 16 + c) << 6) + ks * 32 + g * 8];

  floatx4 zero4 = {0.f, 0.f, 0.f, 0.f};
  floatx4 o[4];
#pragma unroll
  for (int nb = 0; nb < 4; ++nb) o[nb] = zero4;
  float mr[4], lr[4];
#pragma unroll
  for (int r = 0; r < 4; ++r) { mr[r] = -1e30f; lr[r] = 0.f; }

  int srow[2], scol[2];
  float4 rk[2], rv[2];
#pragma unroll
  for (int j = 0; j < 2; ++j) { int idx = tid + j * 512; srow[j] = idx >> 4; scol[j] = (idx & 15) * 4; }

  auto load_tile = [&](int t) {
#pragma unroll
    for (int j = 0; j < 2; ++j) {
      long base = (((long)(t * 64 + srow[j])) << 6) + scol[j];
      rk[j] = *(const float4*)&kcache[base];
      rv[j] = *(const float4*)&vcache[base];
    }
  };
  load_tile(0);

  short* lPw = lP + wid * (16 * 72);
  const int NT = T_T / 64;   // 34

  for (int t = 0; t < NT; ++t) {
    __syncthreads();                         // previous tile's LDS reads done
#pragma unroll
    for (int j = 0; j < 2; ++j) {
      int sidx = (srow[j] * 64 + scol[j]) ^ ((srow[j] & 7) << 3);
      *(short4v*)&lK[sidx] = f2bf4(rk[j]);
      const float* pv = (const float*)&rv[j];
#pragma unroll
      for (int e = 0; e < 4; ++e)            // transpose V into [h][kv]
        lV[(scol[j] + e) * 72 + srow[j]] = f2bf(pv[e]);
    }
    __syncthreads();
    if (t + 1 < NT) load_tile(t + 1);        // prefetch next tile under compute

    // --- QK^T: D[q16][key16], A=Q frag, B=K row-major frag
    floatx4 sc[4];
#pragma unroll
    for (int kb = 0; kb < 4; ++kb) {
      sc[kb] = zero4;
#pragma unroll
      for (int ks = 0; ks < 2; ++ks) {
        int row = kb * 16 + c;
        short8v kf = *(const short8v*)&lK[(row * 64 + ks * 32 + g * 8) ^ ((c & 7) << 3)];
        sc[kb] = __builtin_amdgcn_mfma_f32_16x16x32_bf16(aq[ks], kf, sc[kb], 0, 0, 0);
      }
    }

    // --- online softmax (rows live across 16 lanes of the same quarter-wave)
    float corr[4];
#pragma unroll
    for (int r = 0; r < 4; ++r) {
      float mt = fmaxf(fmaxf(sc[0][r], sc[1][r]), fmaxf(sc[2][r], sc[3][r]));
#pragma unroll
      for (int msk = 1; msk < 16; msk <<= 1)
        mt = fmaxf(mt, __shfl_xor(mt, msk, 64));
      float mnew = fmaxf(mr[r], mt);
      float co = __expf(mr[r] - mnew);
      float ps = 0.f;
#pragma unroll
      for (int kb = 0; kb < 4; ++kb) {
        float p = __expf(sc[kb][r] - mnew);
        sc[kb][r] = p;
        ps += p;
      }
#pragma unroll
      for (int msk = 1; msk < 16; msk <<= 1)
        ps += __shfl_xor(ps, msk, 64);
      lr[r] = lr[r] * co + ps;
      mr[r] = mnew;
      corr[r] = co;
    }
#pragma unroll
    for (int nb = 0; nb < 4; ++nb)
#pragma unroll
      for (int r = 0; r < 4; ++r)
        o[nb][r] *= corr[r];

    // --- P -> wave-private LDS (bf16), then PV
#pragma unroll
    for (int kb = 0; kb < 4; ++kb)
#pragma unroll
      for (int r = 0; r < 4; ++r)
        lPw[(g * 4 + r) * 72 + kb * 16 + c] = f2bf(sc[kb][r]);
    // wave-private region: same-wave DS ops are in-order; fence the compiler
    asm volatile("s_waitcnt lgkmcnt(0)" ::: "memory");

#pragma unroll
    for (int ks = 0; ks < 2; ++ks) {
      short8v ap = *(const short8v*)&lPw[c * 72 + ks * 32 + g * 8];
#pragma unroll
      for (int nb = 0; nb < 4; ++nb) {
        short8v vf = *(const short8v*)&lV[(nb * 16 + c) * 72 + ks * 32 + g * 8];
        o[nb] = __builtin_amdgcn_mfma_f32_16x16x32_bf16(ap, vf, o[nb], 0, 0, 0);
      }
    }
  }

  // --- normalize + write context [s*B+b][n*H+h] f32
  const int b = bn >> 4, nh = bn & 15;
#pragma unroll
  for (int r = 0; r < 4; ++r) {
    float inv = 1.0f / lr[r];
    int s = wid * 16 + g * 4 + r;
#pragma unroll
    for (int nb = 0; nb < 4; ++nb)
      ctx[(long)(s * 16 + b) * 1024 + nh * 64 + nb * 16 + c] = o[nb][r] * inv;
  }
}

// ---------------------------------------------------------------------------
extern "C" void kernel_launch(void* const* d_in, const int* in_sizes, int n_in,
                              void* d_out, int out_size, void* d_ws, size_t ws_size,
                              hipStream_t stream) {
  const float* query = (const float*)d_in[0];
  // d_in[1] ("key") is unused by the reference (projections use query)
  const float* kc = (const float*)d_in[2];
  const float* vc = (const float*)d_in[3];
  const float* Wq = (const float*)d_in[4];
  const float* bq = (const float*)d_in[5];
  const float* Wk = (const float*)d_in[6];
  const float* bk = (const float*)d_in[7];
  const float* Wv = (const float*)d_in[8];
  const float* bv = (const float*)d_in[9];
  const float* Wo = (const float*)d_in[10];
  const float* bo = (const float*)d_in[11];

  float* out = (float*)d_out;
  float* ctx = (float*)d_ws;                                   // 8 MB f32 [2048][1024]
  short* qws = (short*)((char*)d_ws + (size_t)8 * 1024 * 1024); // 4 MB bf16 [256][128][64]

  copy_caches<<<dim3(2048), dim3(256), 0, stream>>>((const float4*)kc, (const float4*)vc, out);
  gemm64<<<dim3(32, 16, 3), dim3(256), 0, stream>>>(query, Wq, bq, Wk, bk, Wv, bv, qws, out, 0);
  attn_kernel<<<dim3(256), dim3(512), 0, stream>>>(qws, out, ctx);
  gemm64<<<dim3(32, 16, 1), dim3(256), 0, stream>>>(ctx, Wo, bo, Wo, bo, Wo, bo, qws, out, 1);
}

// Round 6
// 581.277 us; speedup vs baseline: 1.1127x; 1.1127x over previous
//
#include <hip/hip_runtime.h>

// Problem constants (S=128, B=16, E=1024, N=16, H=64, L=2048, T=2176)
#define S_Q     128
#define B_B     16
#define E_E     1024
#define N_H     16
#define H_D     64
#define L_C     2048
#define T_T     2176
#define BN_H    256      // B*N
#define M_M     2048     // S*B
#define KC_OFF  2097152               // S*B*E
#define VC_OFF  37748736              // KC_OFF + BN*T*H

typedef __attribute__((ext_vector_type(8))) short short8v;   // 8 bf16 (4 VGPRs) MFMA frag
typedef __attribute__((ext_vector_type(4))) short short4v;
typedef __attribute__((ext_vector_type(4))) float floatx4;   // MFMA accumulator

__device__ __forceinline__ short f2bf(float f) {
  union { float f; unsigned u; } x; x.f = f;
  unsigned r = x.u + 0x7fffu + ((x.u >> 16) & 1u);   // RNE truncate to bf16
  return (short)(r >> 16);
}
__device__ __forceinline__ short4v f2bf4(float4 v) {
  short4v r; r.x = f2bf(v.x); r.y = f2bf(v.y); r.z = f2bf(v.z); r.w = f2bf(v.w);
  return r;
}

// ---------------------------------------------------------------------------
// Kernel 1/3: bf16 MFMA GEMM, C[m,n] = X[m,:] . W[n,:] + bias[n]
// X f32 [2048][1024] row-major, W f32 [1024][1024] row-major (both K-contig).
// Tile 64x64x64, 4 waves, each wave 32x32 (2x2 frags of 16x16x32 MFMA).
// mode 0: z selects {Wq->qws bf16 (scaled), Wk->kcache tail, Wv->vcache tail}
// mode 1: plain f32 store to obase (output projection)
// ---------------------------------------------------------------------------
__global__ __launch_bounds__(256) void gemm64(
    const float* __restrict__ X,
    const float* __restrict__ W0, const float* __restrict__ Bi0,
    const float* __restrict__ W1, const float* __restrict__ Bi1,
    const float* __restrict__ W2, const float* __restrict__ Bi2,
    short* __restrict__ qws, float* __restrict__ obase, int mode)
{
  __shared__ short lA[64 * 64];
  __shared__ short lB[64 * 64];
  const int z   = blockIdx.z;
  const float* W  = (z == 0) ? W0 : (z == 1) ? W1 : W2;
  const float* Bi = (z == 0) ? Bi0 : (z == 1) ? Bi1 : Bi2;
  const int gr0 = blockIdx.x * 64;
  const int gc0 = blockIdx.y * 64;
  const int tid = threadIdx.x;
  const int lane = tid & 63;
  const int wid  = tid >> 6;
  const int wm = (wid & 1) * 32;
  const int wn = (wid >> 1) * 32;
  const int c = lane & 15;
  const int g = lane >> 4;

  floatx4 zero4 = {0.f, 0.f, 0.f, 0.f};
  floatx4 acc[2][2];
  acc[0][0] = zero4; acc[0][1] = zero4; acc[1][0] = zero4; acc[1][1] = zero4;

  int srow[4], scol[4];
  float4 ra[4], rb[4];
#pragma unroll
  for (int j = 0; j < 4; ++j) { int idx = tid + j * 256; srow[j] = idx >> 4; scol[j] = (idx & 15) * 4; }

  auto stage_load = [&](int kt) {
#pragma unroll
    for (int j = 0; j < 4; ++j) {
      ra[j] = *(const float4*)&X[(long)(gr0 + srow[j]) * 1024 + kt * 64 + scol[j]];
      rb[j] = *(const float4*)&W[(long)(gc0 + srow[j]) * 1024 + kt * 64 + scol[j]];
    }
  };
  stage_load(0);

  for (int kt = 0; kt < 16; ++kt) {
    __syncthreads();                       // LDS free from previous compute
#pragma unroll
    for (int j = 0; j < 4; ++j) {
      int sidx = (srow[j] * 64 + scol[j]) ^ ((srow[j] & 7) << 3);   // XOR swizzle (G4)
      *(short4v*)&lA[sidx] = f2bf4(ra[j]);
      *(short4v*)&lB[sidx] = f2bf4(rb[j]);
    }
    __syncthreads();
    if (kt < 15) stage_load(kt + 1);       // prefetch overlaps MFMA below
#pragma unroll
    for (int ks = 0; ks < 2; ++ks) {
      short8v af[2], bf[2];
#pragma unroll
      for (int mi = 0; mi < 2; ++mi) {
        int row = wm + mi * 16 + c;
        af[mi] = *(const short8v*)&lA[(row * 64 + ks * 32 + g * 8) ^ ((c & 7) << 3)];
      }
#pragma unroll
      for (int ni = 0; ni < 2; ++ni) {
        int row = wn + ni * 16 + c;
        bf[ni] = *(const short8v*)&lB[(row * 64 + ks * 32 + g * 8) ^ ((c & 7) << 3)];
      }
#pragma unroll
      for (int mi = 0; mi < 2; ++mi)
#pragma unroll
        for (int ni = 0; ni < 2; ++ni)
          acc[mi][ni] = __builtin_amdgcn_mfma_f32_16x16x32_bf16(af[mi], bf[ni], acc[mi][ni], 0, 0, 0);
    }
  }

  // Epilogue. C/D layout: col = lane&15, row = (lane>>4)*4 + reg   [m89]
#pragma unroll
  for (int mi = 0; mi < 2; ++mi) {
#pragma unroll
    for (int ni = 0; ni < 2; ++ni) {
#pragma unroll
      for (int r = 0; r < 4; ++r) {
        int m = gr0 + wm + mi * 16 + g * 4 + r;
        int n = gc0 + wn + ni * 16 + c;
        float v = acc[mi][ni][r] + Bi[n];
        if (mode == 1) {
          obase[(long)m * 1024 + n] = v;
        } else {
          int s = m >> 4, b = m & 15, nh = n >> 6, h = n & 63;
          if (z == 0) {
            // q scaled by H^-0.5, bf16, layout [b*N+n][s][h]
            qws[(((long)(b * 16 + nh) * 128 + s) << 6) + h] = f2bf(v * 0.125f);
          } else {
            long off = (z == 1) ? (long)KC_OFF : (long)VC_OFF;
            obase[off + (((long)(b * 16 + nh) * T_T + L_C + s) << 6) + h] = v;
          }
        }
      }
    }
  }
}

// ---------------------------------------------------------------------------
// Kernel 2: flash attention FUSED with the cache copy. 1 block per head
// (256 blocks), 512 threads (8 waves x 16 q-rows). Tiles t=0..31 stream K/V
// rows 0..2047 from the ORIGINAL input caches and store them to d_out (the
// concat copy) while staging f32->bf16 into LDS; tiles 32,33 read the tail
// rows (written by gemm0) from d_out. Online softmax as before.
// ---------------------------------------------------------------------------
__global__ __launch_bounds__(512) void attn_fused(const short* __restrict__ qws,
                                                  const float* __restrict__ kc_in,
                                                  const float* __restrict__ vc_in,
                                                  float* __restrict__ dout,
                                                  float* __restrict__ ctx)
{
  __shared__ short lK[64 * 64];
  __shared__ short lV[64 * 72];         // V^T [h][kv], rows padded to 72
  __shared__ short lP[8 * 16 * 72];     // per-wave P [16 q][64 keys], padded

  const int bn = blockIdx.x;
  const int tid = threadIdx.x;
  const int lane = tid & 63;
  const int wid  = tid >> 6;
  const int c = lane & 15;
  const int g = lane >> 4;

  const float* ksrc = kc_in + (long)bn * (L_C * H_D);   // [B*N][L][H] input
  const float* vsrc = vc_in + (long)bn * (L_C * H_D);
  float* kdst = dout + KC_OFF + (long)bn * (T_T * H_D); // [B*N][T][H] output
  float* vdst = dout + VC_OFF + (long)bn * (T_T * H_D);

  // Q A-frags, held in registers for the whole loop
  short8v aq[2];
#pragma unroll
  for (int ks = 0; ks < 2; ++ks)
    aq[ks] = *(const short8v*)&qws[(((long)bn * 128 + wid * 16 + c) << 6) + ks * 32 + g * 8];

  floatx4 zero4 = {0.f, 0.f, 0.f, 0.f};
  floatx4 o[4];
#pragma unroll
  for (int nb = 0; nb < 4; ++nb) o[nb] = zero4;
  float mr[4], lr[4];
#pragma unroll
  for (int r = 0; r < 4; ++r) { mr[r] = -1e30f; lr[r] = 0.f; }

  int srow[2], scol[2];
  float4 rk[2], rv[2];
#pragma unroll
  for (int j = 0; j < 2; ++j) { int idx = tid + j * 512; srow[j] = idx >> 4; scol[j] = (idx & 15) * 4; }

  const int NT = T_T / 64;   // 34; tiles 0..31 from input (copied), 32..33 tail
  auto load_tile = [&](int t) {
    if (t < 32) {
#pragma unroll
      for (int j = 0; j < 2; ++j) {
        long base = (((long)(t * 64 + srow[j])) << 6) + scol[j];
        rk[j] = *(const float4*)&ksrc[base];
        rv[j] = *(const float4*)&vsrc[base];
      }
    } else {
#pragma unroll
      for (int j = 0; j < 2; ++j) {
        long base = (((long)(t * 64 + srow[j])) << 6) + scol[j];
        rk[j] = *(const float4*)&kdst[base];
        rv[j] = *(const float4*)&vdst[base];
      }
    }
  };
  load_tile(0);

  short* lPw = lP + wid * (16 * 72);

  for (int t = 0; t < NT; ++t) {
    __syncthreads();                         // previous tile's LDS reads done
#pragma unroll
    for (int j = 0; j < 2; ++j) {
      int sidx = (srow[j] * 64 + scol[j]) ^ ((srow[j] & 7) << 3);
      *(short4v*)&lK[sidx] = f2bf4(rk[j]);
      const float* pv = (const float*)&rv[j];
#pragma unroll
      for (int e = 0; e < 4; ++e)            // transpose V into [h][kv]
        lV[(scol[j] + e) * 72 + srow[j]] = f2bf(pv[e]);
    }
    if (t < 32) {                            // fused cache copy (rows 0..2047)
#pragma unroll
      for (int j = 0; j < 2; ++j) {
        long base = (((long)(t * 64 + srow[j])) << 6) + scol[j];
        *(float4*)&kdst[base] = rk[j];
        *(float4*)&vdst[base] = rv[j];
      }
    }
    if (t + 1 < NT) load_tile(t + 1);        // prefetch issues BEFORE barrier
    __syncthreads();

    // --- QK^T: D[q16][key16], A=Q frag, B=K row-major frag
    floatx4 sc[4];
    __builtin_amdgcn_s_setprio(1);
#pragma unroll
    for (int kb = 0; kb < 4; ++kb) {
      sc[kb] = zero4;
#pragma unroll
      for (int ks = 0; ks < 2; ++ks) {
        int row = kb * 16 + c;
        short8v kf = *(const short8v*)&lK[(row * 64 + ks * 32 + g * 8) ^ ((c & 7) << 3)];
        sc[kb] = __builtin_amdgcn_mfma_f32_16x16x32_bf16(aq[ks], kf, sc[kb], 0, 0, 0);
      }
    }
    __builtin_amdgcn_s_setprio(0);

    // --- online softmax (rows live across 16 lanes of the same quarter-wave)
    float corr[4];
#pragma unroll
    for (int r = 0; r < 4; ++r) {
      float mt = fmaxf(fmaxf(sc[0][r], sc[1][r]), fmaxf(sc[2][r], sc[3][r]));
#pragma unroll
      for (int msk = 1; msk < 16; msk <<= 1)
        mt = fmaxf(mt, __shfl_xor(mt, msk, 64));
      float mnew = fmaxf(mr[r], mt);
      float co = __expf(mr[r] - mnew);
      float ps = 0.f;
#pragma unroll
      for (int kb = 0; kb < 4; ++kb) {
        float p = __expf(sc[kb][r] - mnew);
        sc[kb][r] = p;
        ps += p;
      }
#pragma unroll
      for (int msk = 1; msk < 16; msk <<= 1)
        ps += __shfl_xor(ps, msk, 64);
      lr[r] = lr[r] * co + ps;
      mr[r] = mnew;
      corr[r] = co;
    }
#pragma unroll
    for (int nb = 0; nb < 4; ++nb)
#pragma unroll
      for (int r = 0; r < 4; ++r)
        o[nb][r] *= corr[r];

    // --- P -> wave-private LDS (bf16), then PV
#pragma unroll
    for (int kb = 0; kb < 4; ++kb)
#pragma unroll
      for (int r = 0; r < 4; ++r)
        lPw[(g * 4 + r) * 72 + kb * 16 + c] = f2bf(sc[kb][r]);
    // wave-private region: same-wave DS ops are in-order; fence the compiler
    asm volatile("s_waitcnt lgkmcnt(0)" ::: "memory");

    __builtin_amdgcn_s_setprio(1);
#pragma unroll
    for (int ks = 0; ks < 2; ++ks) {
      short8v ap = *(const short8v*)&lPw[c * 72 + ks * 32 + g * 8];
#pragma unroll
      for (int nb = 0; nb < 4; ++nb) {
        short8v vf = *(const short8v*)&lV[(nb * 16 + c) * 72 + ks * 32 + g * 8];
        o[nb] = __builtin_amdgcn_mfma_f32_16x16x32_bf16(ap, vf, o[nb], 0, 0, 0);
      }
    }
    __builtin_amdgcn_s_setprio(0);
  }

  // --- normalize + write context [s*B+b][n*H+h] f32
  const int b = bn >> 4, nh = bn & 15;
#pragma unroll
  for (int r = 0; r < 4; ++r) {
    float inv = 1.0f / lr[r];
    int s = wid * 16 + g * 4 + r;
#pragma unroll
    for (int nb = 0; nb < 4; ++nb)
      ctx[(long)(s * 16 + b) * 1024 + nh * 64 + nb * 16 + c] = o[nb][r] * inv;
  }
}

// ---------------------------------------------------------------------------
extern "C" void kernel_launch(void* const* d_in, const int* in_sizes, int n_in,
                              void* d_out, int out_size, void* d_ws, size_t ws_size,
                              hipStream_t stream) {
  const float* query = (const float*)d_in[0];
  // d_in[1] ("key") is unused by the reference (projections use query)
  const float* kc = (const float*)d_in[2];
  const float* vc = (const float*)d_in[3];
  const float* Wq = (const float*)d_in[4];
  const float* bq = (const float*)d_in[5];
  const float* Wk = (const float*)d_in[6];
  const float* bk = (const float*)d_in[7];
  const float* Wv = (const float*)d_in[8];
  const float* bv = (const float*)d_in[9];
  const float* Wo = (const float*)d_in[10];
  const float* bo = (const float*)d_in[11];

  float* out = (float*)d_out;
  float* ctx = (float*)d_ws;                                   // 8 MB f32 [2048][1024]
  short* qws = (short*)((char*)d_ws + (size_t)8 * 1024 * 1024); // 4 MB bf16 [256][128][64]

  gemm64<<<dim3(32, 16, 3), dim3(256), 0, stream>>>(query, Wq, bq, Wk, bk, Wv, bv, qws, out, 0);
  attn_fused<<<dim3(256), dim3(512), 0, stream>>>(qws, kc, vc, out, ctx);
  gemm64<<<dim3(32, 16, 1), dim3(256), 0, stream>>>(ctx, Wo, bo, Wo, bo, Wo, bo, qws, out, 1);
}